// Round 1
// baseline (342.930 us; speedup 1.0000x reference)
//
#include <hip/hip_runtime.h>

#define NB 8
#define CC 3
#define HH 720
#define WW 1280
#define EPSL 1e-6f
#define HSEG 40   // 720 = 18*40 -> 18 h-segments in pass 2

// ---- per-pixel channel sums: left (sl,ql) and warped-right (sr,qr) ----
__device__ __forceinline__ void pixel_sums(
    const float* __restrict__ left, const float* __restrict__ right,
    const float* __restrict__ disp, int n, int h, int col,
    float& sl, float& ql, float& sr, float& qr)
{
    sl = ql = sr = qr = 0.f;
    if (col < 0 || col >= WW) return;               // zero padding of the maps
    const size_t plane = (size_t)HH * WW;
    size_t lbase = ((size_t)n * CC) * plane + (size_t)h * WW;
    float l0 = left[lbase + col];
    float l1 = left[lbase + plane + col];
    float l2 = left[lbase + 2 * plane + col];
    sl = l0 + l1 + l2;
    ql = l0 * l0 + l1 * l1 + l2 * l2;

    float d  = disp[(size_t)n * plane + (size_t)h * WW + col];
    float ix = (float)col - d;
    float x0 = floorf(ix);
    float wx = ix - x0;
    int x0i = (int)x0;
    int x1i = x0i + 1;
    float v0 = (x0i >= 0 && x0i < WW) ? 1.f : 0.f;
    float v1 = (x1i >= 0 && x1i < WW) ? 1.f : 0.f;
    int i0 = min(max(x0i, 0), WW - 1);
    int i1 = min(max(x1i, 0), WW - 1);
    float w0v = v0 * (1.f - wx);
    float w1v = v1 * wx;
#pragma unroll
    for (int c = 0; c < CC; ++c) {
        size_t rb = lbase + (size_t)c * plane;
        float g0 = right[rb + i0];
        float g1 = right[rb + i1];
        float rc = g0 * w0v + g1 * w1v;
        sr += rc;
        qr += rc * rc;
    }
}

// ---- Pass 1: channel sums + horizontal 9-tap box, write 4 maps ----
__global__ __launch_bounds__(256)
void hbox_kernel(const float* __restrict__ left, const float* __restrict__ right,
                 const float* __restrict__ disp,
                 float* __restrict__ SL, float* __restrict__ QL,
                 float* __restrict__ SR, float* __restrict__ QR)
{
    __shared__ float s_sl[264], s_ql[264], s_sr[264], s_qr[264];
    const int t = threadIdx.x;           // 0..255
    const int w0 = blockIdx.x * 256;     // 0,256,...,1024 (1280/256 = 5)
    const int h  = blockIdx.y;
    const int n  = blockIdx.z;

    float sl, ql, sr, qr;
    pixel_sums(left, right, disp, n, h, w0 - 4 + t, sl, ql, sr, qr);
    s_sl[t] = sl; s_ql[t] = ql; s_sr[t] = sr; s_qr[t] = qr;
    if (t < 8) {
        pixel_sums(left, right, disp, n, h, w0 + 252 + t, sl, ql, sr, qr);
        s_sl[256 + t] = sl; s_ql[256 + t] = ql; s_sr[256 + t] = sr; s_qr[256 + t] = qr;
    }
    __syncthreads();

    float a = 0.f, b = 0.f, c = 0.f, d = 0.f;
#pragma unroll
    for (int k = 0; k < 9; ++k) {        // s index t+k == column w0+t-4+k
        a += s_sl[t + k];
        b += s_ql[t + k];
        c += s_sr[t + k];
        d += s_qr[t + k];
    }
    size_t idx = ((size_t)n * HH + h) * WW + w0 + t;
    SL[idx] = a; QL[idx] = b; SR[idx] = c; QR[idx] = d;
}

// ---- Pass 2: vertical rolling 9-row box + LCN diff + reduction ----
__global__ __launch_bounds__(256)
void loss_kernel(const float* __restrict__ left, const float* __restrict__ right,
                 const float* __restrict__ disp,
                 const float* __restrict__ SL, const float* __restrict__ QL,
                 const float* __restrict__ SR, const float* __restrict__ QR,
                 float* __restrict__ out)
{
    const int t  = threadIdx.x;
    const int w  = blockIdx.x * 256 + t;     // 5 chunks
    const int h0 = blockIdx.y * HSEG;        // 18 segments
    const int n  = blockIdx.z;
    const size_t plane = (size_t)HH * WW;
    const size_t mapb  = (size_t)n * plane + w;

    float vsl = 0.f, vql = 0.f, vsr = 0.f, vqr = 0.f;
    for (int r = h0 - 4; r < h0 + 4; ++r) {
        if (r >= 0 && r < HH) {
            size_t i = mapb + (size_t)r * WW;
            vsl += SL[i]; vql += QL[i]; vsr += SR[i]; vqr += QR[i];
        }
    }

    float acc = 0.f;
    for (int h = h0; h < h0 + HSEG; ++h) {
        int rn = h + 4;
        if (rn < HH) {
            size_t i = mapb + (size_t)rn * WW;
            vsl += SL[i]; vql += QL[i]; vsr += SR[i]; vqr += QR[i];
        }

        float ml   = vsl * (1.f / 81.f);
        float msl  = vql * (1.f / 81.f);
        float stdl = (msl - ml * ml) * (81.f / 80.f);
        float invl = 1.f / (stdl + EPSL);
        float mr   = vsr * (1.f / 81.f);
        float msr  = vqr * (1.f / 81.f);
        float stdr = (msr - mr * mr) * (81.f / 80.f);
        float invr = 1.f / (stdr + EPSL);

        float d  = disp[(size_t)n * plane + (size_t)h * WW + w];
        float ix = (float)w - d;
        float x0 = floorf(ix);
        float wx = ix - x0;
        int x0i = (int)x0;
        int x1i = x0i + 1;
        float v0 = (x0i >= 0 && x0i < WW) ? 1.f : 0.f;
        float v1 = (x1i >= 0 && x1i < WW) ? 1.f : 0.f;
        int i0 = min(max(x0i, 0), WW - 1);
        int i1 = min(max(x1i, 0), WW - 1);
        float w0v = v0 * (1.f - wx);
        float w1v = v1 * wx;

#pragma unroll
        for (int cch = 0; cch < CC; ++cch) {
            size_t rowb = ((size_t)(n * CC + cch)) * plane + (size_t)h * WW;
            float lc = left[rowb + w];
            float g0 = right[rowb + i0];
            float g1 = right[rowb + i1];
            float rc = g0 * w0v + g1 * w1v;
            float av = (lc - ml) * invl;
            float bv = (rc - mr) * invr;
            acc += fabsf((av - bv) * stdl);
        }

        int ro = h - 4;
        if (ro >= 0) {
            size_t i = mapb + (size_t)ro * WW;
            vsl -= SL[i]; vql -= QL[i]; vsr -= SR[i]; vqr -= QR[i];
        }
    }

    __shared__ float red[256];
    red[t] = acc;
    __syncthreads();
    for (int s = 128; s > 0; s >>= 1) {
        if (t < s) red[t] += red[t + s];
        __syncthreads();
    }
    if (t == 0) {
        const float inv_count = 1.f / ((float)NB * CC * HH * WW);
        atomicAdd(out, red[0] * inv_count);
    }
}

extern "C" void kernel_launch(void* const* d_in, const int* in_sizes, int n_in,
                              void* d_out, int out_size, void* d_ws, size_t ws_size,
                              hipStream_t stream) {
    const float* left  = (const float*)d_in[0];
    const float* right = (const float*)d_in[1];
    const float* disp  = (const float*)d_in[2];
    float* out = (float*)d_out;

    const size_t map_elems = (size_t)NB * HH * WW;   // 7,372,800 floats
    float* SL = (float*)d_ws;
    float* QL = SL + map_elems;
    float* SR = QL + map_elems;
    float* QR = SR + map_elems;

    hipMemsetAsync(out, 0, sizeof(float) * out_size, stream);

    dim3 grid1(WW / 256, HH, NB);   // (5, 720, 8)
    hipLaunchKernelGGL(hbox_kernel, grid1, dim3(256), 0, stream,
                       left, right, disp, SL, QL, SR, QR);

    dim3 grid2(WW / 256, HH / HSEG, NB);  // (5, 18, 8)
    hipLaunchKernelGGL(loss_kernel, grid2, dim3(256), 0, stream,
                       left, right, disp, SL, QL, SR, QR, out);
}

// Round 3
// 303.323 us; speedup vs baseline: 1.1306x; 1.1306x over previous
//
#include <hip/hip_runtime.h>

#define NB 8
#define CC 3
#define HH 720
#define WW 1280
#define EPSL 1e-6f
#define HSEG 45      // output rows per block strip; 720 = 16*45
#define TILE_OUT 248 // output cols per block (256 threads - 8 halo)
#define NTILE 6      // 6*248 >= 1280

// per-pixel channel sums: (SL, QL, SR, QR), zero outside image.
// EXACT round-1 arithmetic: plain mul+add, v0/v1 multiplicative masks.
__device__ __forceinline__ float4 pixel_sums(
    const float* __restrict__ left, const float* __restrict__ right,
    const float* __restrict__ disp, int n, int r, int gc)
{
    float4 v = make_float4(0.f, 0.f, 0.f, 0.f);
    if (r < 0 || r >= HH || gc < 0 || gc >= WW) return v;
    const size_t plane = (size_t)HH * WW;
    size_t lb = (size_t)n * CC * plane + (size_t)r * WW + gc;
    float l0 = left[lb], l1 = left[lb + plane], l2 = left[lb + 2 * plane];
    v.x = l0 + l1 + l2;
    v.y = l0 * l0 + l1 * l1 + l2 * l2;

    float d  = disp[(size_t)n * plane + (size_t)r * WW + gc];
    float ix = (float)gc - d;
    float x0 = floorf(ix);
    float wx = ix - x0;
    int x0i = (int)x0, x1i = x0i + 1;
    float v0 = (x0i >= 0 && x0i < WW) ? 1.f : 0.f;
    float v1 = (x1i >= 0 && x1i < WW) ? 1.f : 0.f;
    int i0 = min(max(x0i, 0), WW - 1);
    int i1 = min(max(x1i, 0), WW - 1);
    float w0v = v0 * (1.f - wx);
    float w1v = v1 * wx;
    size_t rb = (size_t)n * CC * plane + (size_t)r * WW;
    float sr = 0.f, qr = 0.f;
#pragma unroll
    for (int c = 0; c < CC; ++c) {
        float g0 = right[rb + i0];
        float g1 = right[rb + i1];
        float rc = g0 * w0v + g1 * w1v;
        sr += rc;
        qr += rc * rc;
        rb += plane;
    }
    v.z = sr; v.w = qr;
    return v;
}

__global__ __launch_bounds__(256)
void fused_loss_kernel(const float* __restrict__ left,
                       const float* __restrict__ right,
                       const float* __restrict__ disp,
                       float* __restrict__ out)
{
    // stage: raw per-pixel sums for one row (halo included) -> fresh h-box.
    // ring: 9-deep thread-private vertical window of h-boxed values.
    __shared__ float4 ring[9 * 256];   // 36 KB
    __shared__ float4 stage[256];      // 4 KB
    __shared__ float  red[256];        // 1 KB  -> ~41 KB, 3 blocks/CU

    const int t  = threadIdx.x;
    const int gc = blockIdx.x * TILE_OUT + t - 4;   // owned column
    const int h0 = blockIdx.y * HSEG;
    const int n  = blockIdx.z;
    const size_t plane = (size_t)HH * WW;
    const bool out_thread = (t >= 4) && (t < 4 + TILE_OUT) && (gc < WW);

    float4 vsum = make_float4(0.f, 0.f, 0.f, 0.f);
    float acc = 0.f;

    for (int iter = 0; iter < HSEG + 8; ++iter) {
        const int r = h0 - 4 + iter;
        float4 raw = pixel_sums(left, right, disp, n, r, gc);

        __syncthreads();                 // previous iter's stage reads done
        stage[t] = raw;
        __syncthreads();

        // fresh horizontal 9-sum (round-1 pass-1 association)
        float4 hrow = make_float4(0.f, 0.f, 0.f, 0.f);
        if (out_thread) {
            hrow = stage[t - 4];
#pragma unroll
            for (int k = 1; k < 9; ++k) {
                float4 s = stage[t - 4 + k];
                hrow.x += s.x; hrow.y += s.y; hrow.z += s.z; hrow.w += s.w;
            }
        }

        // round-1 pass-2 cadence: add new, compute, subtract old
        ring[(iter % 9) * 256 + t] = hrow;
        vsum.x += hrow.x; vsum.y += hrow.y; vsum.z += hrow.z; vsum.w += hrow.w;

        if (iter >= 8) {
            if (out_thread) {
                const int h = r - 4;
                float ml   = vsum.x * (1.f / 81.f);
                float msl  = vsum.y * (1.f / 81.f);
                float stdl = (msl - ml * ml) * (81.f / 80.f);
                float invl = 1.f / (stdl + EPSL);
                float mr   = vsum.z * (1.f / 81.f);
                float msr  = vsum.w * (1.f / 81.f);
                float stdr = (msr - mr * mr) * (81.f / 80.f);
                float invr = 1.f / (stdr + EPSL);

                // reload center-row pixels (L2-hot: staged 4 iters ago)
                float d  = disp[(size_t)n * plane + (size_t)h * WW + gc];
                float ix = (float)gc - d;
                float x0 = floorf(ix);
                float wx = ix - x0;
                int x0i = (int)x0, x1i = x0i + 1;
                float v0 = (x0i >= 0 && x0i < WW) ? 1.f : 0.f;
                float v1 = (x1i >= 0 && x1i < WW) ? 1.f : 0.f;
                int i0 = min(max(x0i, 0), WW - 1);
                int i1 = min(max(x1i, 0), WW - 1);
                float w0v = v0 * (1.f - wx);
                float w1v = v1 * wx;
                size_t rowb = (size_t)n * CC * plane + (size_t)h * WW;
#pragma unroll
                for (int c = 0; c < CC; ++c) {
                    float lc = left[rowb + gc];
                    float g0 = right[rowb + i0];
                    float g1 = right[rowb + i1];
                    float rc = g0 * w0v + g1 * w1v;
                    float av = (lc - ml) * invl;
                    float bv = (rc - mr) * invr;
                    acc += fabsf((av - bv) * stdl);
                    rowb += plane;
                }
            }
            // subtract row pushed 8 iters ago (slot (iter+1)%9)
            float4 old = ring[((iter + 1) % 9) * 256 + t];
            vsum.x -= old.x; vsum.y -= old.y; vsum.z -= old.z; vsum.w -= old.w;
        }
    }

    red[t] = acc;
    __syncthreads();
#pragma unroll
    for (int s = 128; s > 0; s >>= 1) {
        if (t < s) red[t] += red[t + s];
        __syncthreads();
    }
    if (t == 0) {
        const float inv_count = 1.f / ((float)NB * CC * HH * WW);
        atomicAdd(out, red[0] * inv_count);
    }
}

extern "C" void kernel_launch(void* const* d_in, const int* in_sizes, int n_in,
                              void* d_out, int out_size, void* d_ws, size_t ws_size,
                              hipStream_t stream) {
    const float* left  = (const float*)d_in[0];
    const float* right = (const float*)d_in[1];
    const float* disp  = (const float*)d_in[2];
    float* out = (float*)d_out;

    hipMemsetAsync(out, 0, sizeof(float) * out_size, stream);

    dim3 grid(NTILE, HH / HSEG, NB);   // (6, 16, 8) = 768 blocks = 256 CU * 3
    hipLaunchKernelGGL(fused_loss_kernel, grid, dim3(256), 0, stream,
                       left, right, disp, out);
}

// Round 4
// 235.793 us; speedup vs baseline: 1.4544x; 1.2864x over previous
//
#include <hip/hip_runtime.h>

#define NB 8
#define CC 3
#define HH 720
#define WW 1280
#define EPSL 1e-6f
#define HSEG 45            // 720 = 16*45
#define NSEG (HH / HSEG)   // 16
#define OUTC 56            // output cols per wave (64 lanes - 8 halo)
#define NSTRIP 23          // 23*56 = 1288 >= 1280
#define NITER (HSEG + 8)   // 53
#define NUNIT (NSTRIP * NSEG * NB)  // 2944 waves
#define NBLK (NUNIT / 4)            // 736 blocks

__global__ __launch_bounds__(256)
void fused_loss_kernel(const float* __restrict__ left,
                       const float* __restrict__ right,
                       const float* __restrict__ disp,
                       float* __restrict__ out)
{
    const int t    = threadIdx.x;
    const int lane = t & 63;
    const int u    = blockIdx.x * 4 + (t >> 6);
    const int strip = u % NSTRIP;
    const int hseg  = (u / NSTRIP) % NSEG;
    const int n     = u / (NSTRIP * NSEG);
    const int h0 = hseg * HSEG;
    const int gc  = strip * OUTC + lane - 4;          // column this lane owns
    const int gcc = min(max(gc, 0), WW - 1);          // clamped (safe addresses)
    const bool out_lane = (lane >= 4) && (lane < 4 + OUTC) && (gc < WW);
    const size_t plane = (size_t)HH * WW;
    const float* __restrict__ dispn  = disp  + (size_t)n * plane;
    const float* __restrict__ leftn  = left  + (size_t)n * CC * plane;
    const float* __restrict__ rightn = right + (size_t)n * CC * plane;

    // vertical rolling ring (h-boxed rows, delay 8) — registers
    float4 rg1 = make_float4(0.f,0.f,0.f,0.f);
    float4 rg2=rg1, rg3=rg1, rg4=rg1, rg5=rg1, rg6=rg1, rg7=rg1, rg8=rg1;
    // center-row pixel chain (delay 4): left c0..c2, warped-right c0..c2
    float p1l0=0,p1l1=0,p1l2=0,p1r0=0,p1r1=0,p1r2=0;
    float p2l0=0,p2l1=0,p2l2=0,p2r0=0,p2r1=0,p2r2=0;
    float p3l0=0,p3l1=0,p3l2=0,p3r0=0,p3r1=0,p3r2=0;
    float p4l0=0,p4l1=0,p4l2=0,p4r0=0,p4r1=0,p4r2=0;

    const int r0 = h0 - 4;

    // ---- prologue: rows r0 and r0+1 ----
    int rcl = min(max(r0, 0), HH - 1);
    size_t ro = (size_t)rcl * WW + gcc;
    float dA  = dispn[ro];
    float al0 = leftn[ro], al1 = leftn[plane + ro], al2 = leftn[2*plane + ro];
    rcl = min(max(r0 + 1, 0), HH - 1);
    ro  = (size_t)rcl * WW + gcc;
    float dB  = dispn[ro];
    float bl0 = leftn[ro], bl1 = leftn[plane + ro], bl2 = leftn[2*plane + ro];

    float aw0, aw1, ag00, ag01, ag10, ag11, ag20, ag21;
    {
        float ix  = (float)gc - dA;
        float x0f = floorf(ix), wx = ix - x0f;
        int x0i = (int)x0f, x1i = x0i + 1;
        float v0 = (x0i >= 0 && x0i < WW) ? 1.f : 0.f;
        float v1 = (x1i >= 0 && x1i < WW) ? 1.f : 0.f;
        int i0 = min(max(x0i, 0), WW - 1), i1 = min(max(x1i, 0), WW - 1);
        aw0 = v0 * (1.f - wx); aw1 = v1 * wx;
        size_t rb = (size_t)min(max(r0, 0), HH - 1) * WW;
        ag00 = rightn[rb + i0];           ag01 = rightn[rb + i1];
        ag10 = rightn[plane + rb + i0];   ag11 = rightn[plane + rb + i1];
        ag20 = rightn[2*plane + rb + i0]; ag21 = rightn[2*plane + rb + i1];
    }

    float4 vsum = make_float4(0.f,0.f,0.f,0.f);
    float acc = 0.f;

    for (int iter = 0; iter < NITER; ++iter) {
        const int r = r0 + iter;

        // (1) issue loads for row r+2 (consumed next iter)
        int rcl2 = min(max(r + 2, 0), HH - 1);
        size_t ro2 = (size_t)rcl2 * WW + gcc;
        float dC  = dispn[ro2];
        float cl0 = leftn[ro2], cl1 = leftn[plane + ro2], cl2 = leftn[2*plane + ro2];

        // (2) issue gathers for row r+1 using dB (loaded last iter)
        float bw0, bw1, bg00, bg01, bg10, bg11, bg20, bg21;
        {
            float ix  = (float)gc - dB;
            float x0f = floorf(ix), wx = ix - x0f;
            int x0i = (int)x0f, x1i = x0i + 1;
            float v0 = (x0i >= 0 && x0i < WW) ? 1.f : 0.f;
            float v1 = (x1i >= 0 && x1i < WW) ? 1.f : 0.f;
            int i0 = min(max(x0i, 0), WW - 1), i1 = min(max(x1i, 0), WW - 1);
            bw0 = v0 * (1.f - wx); bw1 = v1 * wx;
            size_t rb = (size_t)min(max(r + 1, 0), HH - 1) * WW;
            bg00 = rightn[rb + i0];           bg01 = rightn[rb + i1];
            bg10 = rightn[plane + rb + i0];   bg11 = rightn[plane + rb + i1];
            bg20 = rightn[2*plane + rb + i0]; bg21 = rightn[2*plane + rb + i1];
        }

        // (3) combine raw channel sums for row r (gathers issued last iter)
        float rca = ag00*aw0 + ag01*aw1;
        float rcb = ag10*aw0 + ag11*aw1;
        float rcc = ag20*aw0 + ag21*aw1;
        bool valr = (r >= 0) && (r < HH) && (gc >= 0) && (gc < WW);
        float rx = al0 + al1 + al2;
        float ry = al0*al0 + al1*al1 + al2*al2;
        float rz = rca + rcb + rcc;
        float rw = rca*rca + rcb*rcb + rcc*rcc;
        rx = valr ? rx : 0.f;  ry = valr ? ry : 0.f;
        rz = valr ? rz : 0.f;  rw = valr ? rw : 0.f;

        // (4) horizontal 9-sum via lane shuffles (same add order as before)
        const int sb = lane - 4;
        float hx = __shfl(rx, sb, 64);
        float hy = __shfl(ry, sb, 64);
        float hz = __shfl(rz, sb, 64);
        float hw = __shfl(rw, sb, 64);
#pragma unroll
        for (int k = 1; k < 9; ++k) {
            hx += __shfl(rx, sb + k, 64);
            hy += __shfl(ry, sb + k, 64);
            hz += __shfl(rz, sb + k, 64);
            hw += __shfl(rw, sb + k, 64);
        }

        // (5) vertical rolling add
        vsum.x += hx; vsum.y += hy; vsum.z += hz; vsum.w += hw;

        // (6) output row h = r-4
        if (iter >= 8) {
            float ml   = vsum.x * (1.f / 81.f);
            float msl  = vsum.y * (1.f / 81.f);
            float stdl = (msl - ml * ml) * (81.f / 80.f);
            float invl = 1.f / (stdl + EPSL);
            float mr   = vsum.z * (1.f / 81.f);
            float msr  = vsum.w * (1.f / 81.f);
            float stdr = (msr - mr * mr) * (81.f / 80.f);
            float invr = 1.f / (stdr + EPSL);
            if (out_lane) {
                float av, bv;
                av = (p4l0 - ml) * invl; bv = (p4r0 - mr) * invr;
                acc += fabsf((av - bv) * stdl);
                av = (p4l1 - ml) * invl; bv = (p4r1 - mr) * invr;
                acc += fabsf((av - bv) * stdl);
                av = (p4l2 - ml) * invl; bv = (p4r2 - mr) * invr;
                acc += fabsf((av - bv) * stdl);
            }
            // (7) subtract h-boxed row pushed 8 iters ago
            vsum.x -= rg8.x; vsum.y -= rg8.y; vsum.z -= rg8.z; vsum.w -= rg8.w;
        }

        // (8) shift rings
        rg8 = rg7; rg7 = rg6; rg6 = rg5; rg5 = rg4; rg4 = rg3; rg3 = rg2; rg2 = rg1;
        rg1 = make_float4(hx, hy, hz, hw);
        p4l0=p3l0; p4l1=p3l1; p4l2=p3l2; p4r0=p3r0; p4r1=p3r1; p4r2=p3r2;
        p3l0=p2l0; p3l1=p2l1; p3l2=p2l2; p3r0=p2r0; p3r1=p2r1; p3r2=p2r2;
        p2l0=p1l0; p2l1=p1l1; p2l2=p1l2; p2r0=p1r0; p2r1=p1r1; p2r2=p1r2;
        p1l0=al0;  p1l1=al1;  p1l2=al2;  p1r0=rca;  p1r1=rcb;  p1r2=rcc;

        // (9) rotate packets: B -> A (row r+1 becomes current), C -> B
        al0=bl0; al1=bl1; al2=bl2;
        aw0=bw0; aw1=bw1;
        ag00=bg00; ag01=bg01; ag10=bg10; ag11=bg11; ag20=bg20; ag21=bg21;
        dB=dC; bl0=cl0; bl1=cl1; bl2=cl2;
    }

    // ---- reduction: wave shuffle -> LDS (4 slots) -> atomic ----
#pragma unroll
    for (int off = 32; off > 0; off >>= 1)
        acc += __shfl_down(acc, off, 64);
    __shared__ float red[4];
    if (lane == 0) red[t >> 6] = acc;
    __syncthreads();
    if (t == 0) {
        float s = red[0] + red[1] + red[2] + red[3];
        const float inv_count = 1.f / ((float)NB * CC * HH * WW);
        atomicAdd(out, s * inv_count);
    }
}

extern "C" void kernel_launch(void* const* d_in, const int* in_sizes, int n_in,
                              void* d_out, int out_size, void* d_ws, size_t ws_size,
                              hipStream_t stream) {
    const float* left  = (const float*)d_in[0];
    const float* right = (const float*)d_in[1];
    const float* disp  = (const float*)d_in[2];
    float* out = (float*)d_out;

    hipMemsetAsync(out, 0, sizeof(float) * out_size, stream);

    hipLaunchKernelGGL(fused_loss_kernel, dim3(NBLK), dim3(256), 0, stream,
                       left, right, disp, out);
}